// Round 6
// baseline (930.261 us; speedup 1.0000x reference)
//
#include <hip/hip_runtime.h>

// ---------------------------------------------------------------------------
// IPLS partial_fit, algebraically restructured.
//
//   xc0 = r*(x - mu),  r = n/(n+1);  mu_new = x - xc0
//   scan scalars from Grams: PW=P@Wz^T, PP=P@P^T, XW=Wz@xc0, XP=P@xc0,
//     W2=diag(Wz@Wz^T), s0=|xc0|^2, CC=Cz@Cz^T, YC=Cz@yc0, sy0=|yc0|^2
//   recursion keeps running dots A_j=dot(xc,Wz_j), D_j=dot(xc,P_j),
//     AY_j=dot(yc,Cz_j) updated lane-parallel per deflation (no shuffles).
//   big outputs via per-column recurrence driven by (u1,t2,g).
//
// Pipeline (6 launches):
//   gram_partial X : 1024 balanced blocks (BK=64, 35KB LDS, 4 blocks/CU)
//   gram_partial Y : 16 blocks
//   gram_reduceA   : 33x64 blocks, 1024 partials -> 64 mids
//   gram_reduceB   : 64 -> finX, 16 -> finY (no transpose needed)
//   recursion      : 1 wave serial scan, readlane broadcasts only
//   expand         : scalar-column recurrence, 520 blocks x 256
// ---------------------------------------------------------------------------

#define NF 131072
#define NT 2048
#define NL 64

#define PSIZE 8385      // 4096 PW + 4096 PP + 64 XW + 64 XP + 64 W2 + 1 s0
#define NBX 1024
#define NBY 16
#define NMID 64
#define REDK 16
#define BK 64
#define LDST 68         // k-row stride (floats): 16B-aligned b128 reads

// d_out offsets (floats), reference return order
#define O_MUX 0
#define O_MUY 131072
#define O_U   133120
#define O_WZ  133184
#define O_CZ  8521792
#define O_TSS 8652864
#define O_BZ  8652928
#define O_P   8652992

// d_ws offsets (floats)
#define W_FINX 0
#define W_FINY 8385
#define W_COEF 16770    // u1[64] | t2[64] | g[64]

__device__ __forceinline__ float rdlane(float v, int l) {
    return __int_as_float(__builtin_amdgcn_readlane(__float_as_int(v), l));
}
#define FRCP(x) __builtin_amdgcn_rcpf(x)
#define FRSQ(x) __builtin_amdgcn_rsqf(x)

// ---------------------------------------------------------------------------
// Partial Grams over a K-chunk (KC=128 = 2 tiles of BK=64), centering fused.
// 256 threads = 4 waves; each wave a k-quarter; 8x8 per-lane output tile.
// part pointer split: bid<512 -> part0 region, else part1 (scratch split
// across the dead P_new / Wz_new output regions).
__global__ __launch_bounds__(256, 4) void gram_partial(
    const float* __restrict__ A, const float* __restrict__ B,
    const float* __restrict__ xs, const float* __restrict__ mus,
    const int* __restrict__ np, int K, int KC,
    float* __restrict__ part0, float* __restrict__ part1,
    float* __restrict__ vout)
{
    __shared__ float lds[2 * BK * LDST + BK];   // 8768 floats = 35 KB
    float* ldsA = lds;
    float* ldsB = lds + BK * LDST;
    float* ldsV = lds + 2 * BK * LDST;

    const int t    = threadIdx.x;
    const int w    = t >> 6;
    const int lane = t & 63;
    const int j0   = lane & 56;          // A-row base  {0,8,...,56}
    const int i0   = (lane & 7) << 3;    // B-row base  {0,8,...,56}

    const float nf = (float)(*np);
    const float r  = nf / (nf + 1.f);

    float accPW[8][8], accPP[8][8];
    float accXW[8], accXP[8], accW2[8], accS0 = 0.f;
#pragma unroll
    for (int s = 0; s < 8; ++s) {
        accXW[s] = 0.f; accXP[s] = 0.f; accW2[s] = 0.f;
#pragma unroll
        for (int q = 0; q < 8; ++q) { accPW[s][q] = 0.f; accPP[s][q] = 0.f; }
    }

    const int bid    = (int)blockIdx.x;
    const int kbase  = bid * KC;
    const int ntiles = KC / BK;                  // 2
    // staging map: bijective (row, c4) over 64 rows x 16 float4-cols;
    // consecutive lanes hit different rows -> benign write conflicts.
    const int rbase = (t & 7) | ((t >> 4) & 8);  // bits0-2 + bit7 -> 0..15
    const int c4    = ((t >> 3) & 15) << 2;      // 0..60

    for (int tile = 0; tile < ntiles; ++tile) {
        const int k0 = kbase + tile * BK;
        if (tile) __syncthreads();
#pragma unroll
        for (int m = 0; m < 4; ++m) {
            int row = rbase | (m << 4);
            const float4 av = *(const float4*)(A + (size_t)row * K + (k0 + c4));
            const float4 bv = *(const float4*)(B + (size_t)row * K + (k0 + c4));
            ldsA[(c4 + 0) * LDST + row] = av.x;
            ldsA[(c4 + 1) * LDST + row] = av.y;
            ldsA[(c4 + 2) * LDST + row] = av.z;
            ldsA[(c4 + 3) * LDST + row] = av.w;
            ldsB[(c4 + 0) * LDST + row] = bv.x;
            ldsB[(c4 + 1) * LDST + row] = bv.y;
            ldsB[(c4 + 2) * LDST + row] = bv.z;
            ldsB[(c4 + 3) * LDST + row] = bv.w;
        }
        if (t < BK) {
            float val = r * (xs[k0 + t] - mus[k0 + t]);   // centered sample
            ldsV[t] = val;
            vout[k0 + t] = val;                            // stash for expand
        }
        __syncthreads();

        const int kend = w * 16 + 16;
        for (int kk = w * 16; kk < kend; ++kk) {
            const float* bA = ldsA + kk * LDST;
            const float* bB = ldsB + kk * LDST;
            float4 a0 = *(const float4*)(bA + j0);
            float4 a1 = *(const float4*)(bA + j0 + 4);
            float4 b0 = *(const float4*)(bB + i0);
            float4 b1 = *(const float4*)(bB + i0 + 4);
            float4 c0 = *(const float4*)(bA + i0);
            float4 c1 = *(const float4*)(bA + i0 + 4);
            float aj[8] = {a0.x,a0.y,a0.z,a0.w,a1.x,a1.y,a1.z,a1.w};
            float bi[8] = {b0.x,b0.y,b0.z,b0.w,b1.x,b1.y,b1.z,b1.w};
            float ci[8] = {c0.x,c0.y,c0.z,c0.w,c1.x,c1.y,c1.z,c1.w};
#pragma unroll
            for (int s = 0; s < 8; ++s)
#pragma unroll
                for (int q = 0; q < 8; ++q) {
                    accPW[s][q] = fmaf(aj[s], bi[q], accPW[s][q]);
                    accPP[s][q] = fmaf(aj[s], ci[q], accPP[s][q]);
                }
            float vv = ldsV[kk];
            if (j0 == 0) {
#pragma unroll
                for (int q = 0; q < 8; ++q) accXW[q] = fmaf(vv, bi[q], accXW[q]);
            }
            if (j0 == 8) {
#pragma unroll
                for (int q = 0; q < 8; ++q) accW2[q] = fmaf(bi[q], bi[q], accW2[q]);
            }
            if (i0 == 0) {
#pragma unroll
                for (int s = 0; s < 8; ++s) accXP[s] = fmaf(vv, aj[s], accXP[s]);
            }
            if (lane == 16) accS0 = fmaf(vv, vv, accS0);
        }
    }
    __syncthreads();

    // cross-wave reduction in 2048-float chunks (fits 8768-float LDS)
    float* red = lds;
    float* po  = (bid < 512 ? part0 : part1) + (size_t)(bid & 511) * PSIZE;

    // PW rows 0-31
    if (j0 < 32) {
#pragma unroll
        for (int s = 0; s < 8; ++s)
#pragma unroll
            for (int q = 0; q < 8; ++q)
                red[w * 2048 + (j0 + s) * 64 + (i0 + q)] = accPW[s][q];
    }
    __syncthreads();
    for (int o = t; o < 2048; o += 256)
        po[o] = red[o] + red[2048 + o] + red[4096 + o] + red[6144 + o];
    __syncthreads();
    // PW rows 32-63
    if (j0 >= 32) {
#pragma unroll
        for (int s = 0; s < 8; ++s)
#pragma unroll
            for (int q = 0; q < 8; ++q)
                red[w * 2048 + (j0 - 32 + s) * 64 + (i0 + q)] = accPW[s][q];
    }
    __syncthreads();
    for (int o = t; o < 2048; o += 256)
        po[2048 + o] = red[o] + red[2048 + o] + red[4096 + o] + red[6144 + o];
    __syncthreads();
    // PP rows 0-31
    if (j0 < 32) {
#pragma unroll
        for (int s = 0; s < 8; ++s)
#pragma unroll
            for (int q = 0; q < 8; ++q)
                red[w * 2048 + (j0 + s) * 64 + (i0 + q)] = accPP[s][q];
    }
    __syncthreads();
    for (int o = t; o < 2048; o += 256)
        po[4096 + o] = red[o] + red[2048 + o] + red[4096 + o] + red[6144 + o];
    __syncthreads();
    // PP rows 32-63
    if (j0 >= 32) {
#pragma unroll
        for (int s = 0; s < 8; ++s)
#pragma unroll
            for (int q = 0; q < 8; ++q)
                red[w * 2048 + (j0 - 32 + s) * 64 + (i0 + q)] = accPP[s][q];
    }
    __syncthreads();
    for (int o = t; o < 2048; o += 256)
        po[6144 + o] = red[o] + red[2048 + o] + red[4096 + o] + red[6144 + o];
    __syncthreads();
    // extras: XW[64] | XP[64] | W2[64] | s0
    if (j0 == 0) {
#pragma unroll
        for (int q = 0; q < 8; ++q) red[w * 193 + (i0 + q)] = accXW[q];
    }
    if (i0 == 0) {
#pragma unroll
        for (int s = 0; s < 8; ++s) red[w * 193 + 64 + (j0 + s)] = accXP[s];
    }
    if (j0 == 8) {
#pragma unroll
        for (int q = 0; q < 8; ++q) red[w * 193 + 128 + (i0 + q)] = accW2[q];
    }
    if (lane == 16) red[w * 193 + 192] = accS0;
    __syncthreads();
    for (int o = t; o < 193; o += 256)
        po[8192 + o] = red[o] + red[193 + o] + red[386 + o] + red[579 + o];
}

// ---------------------------------------------------------------------------
// Stage A: 1024 partials -> 64 mids (16 each, fully unrolled).
__global__ __launch_bounds__(256) void gram_reduceA(
    const float* __restrict__ part0, const float* __restrict__ part1,
    float* __restrict__ mid)
{
    int ob = (int)blockIdx.x % 33;
    int kb = (int)blockIdx.x / 33;     // 0..63
    int o  = ob * 256 + threadIdx.x;
    if (o >= PSIZE) return;
    const float* p = (kb < 32 ? part0 : part1)
                   + (size_t)((kb & 31) * REDK) * PSIZE + o;
    float s = 0.f;
#pragma unroll
    for (int k = 0; k < REDK; ++k) s += p[(size_t)k * PSIZE];
    mid[(size_t)kb * PSIZE + o] = s;
}

// Stage B: X 64 mids -> finX; Y 16 partials -> finY. No transpose (the
// recursion consumes row-major PW[i][j]=dot(P_i,Wz_j); PP/CC symmetric).
__global__ __launch_bounds__(256) void gram_reduceB(
    const float* __restrict__ mid, const float* __restrict__ partY,
    float* __restrict__ finX, float* __restrict__ finY)
{
    int b = blockIdx.x;
    if (b < 33) {
        int o = b * 256 + threadIdx.x;
        if (o >= PSIZE) return;
        float s = 0.f;
#pragma unroll
        for (int k = 0; k < NMID; ++k) s += mid[(size_t)k * PSIZE + o];
        finX[o] = s;
    } else {
        int o = (b - 33) * 256 + threadIdx.x;
        if (o >= PSIZE) return;
        float s = 0.f;
#pragma unroll
        for (int k = 0; k < NBY; ++k) s += partY[(size_t)k * PSIZE + o];
        finY[o] = s;
    }
}

// ---------------------------------------------------------------------------
// 64-step serial recursion, shuffle-free. Lane j carries running dots
//   A=dot(xc,Wz_j), D=dot(xc,P_j), AY=dot(yc,Cz_j)
// updated per deflation from Gram rows; per-step scalars come from cheap
// uniform v_readlane broadcasts. 256 threads stage inputs into LDS first.
__global__ __launch_bounds__(256) void recursion(
    const float* __restrict__ finX, const float* __restrict__ finY,
    const float* __restrict__ u_in, const float* __restrict__ tss_in,
    const float* __restrict__ bz_in,
    float* __restrict__ out_u, float* __restrict__ out_tss, float* __restrict__ out_bz,
    float* __restrict__ coef)
{
    __shared__ float lx[PSIZE];       // PW | PP | XW | XP | W2 | s0
    __shared__ float ly[PSIZE];       // CC | -- | YC | -- | -- | sy0
    __shared__ float lsc[3 * NL];     // u | tss | bz

    const int t = threadIdx.x;
    for (int o = t; o < PSIZE; o += 256) { lx[o] = finX[o]; ly[o] = finY[o]; }
    if (t < NL) {
        lsc[t]          = u_in[t];
        lsc[NL + t]     = tss_in[t];
        lsc[2 * NL + t] = bz_in[t];
    }
    __syncthreads();
    if (t >= 64) return;
    const int lane = t;

    const float* PW = lx;             // [i*64+j] = dot(P_i, Wz_j)
    const float* PP = lx + 4096;      // [i*64+j] = dot(P_i, P_j)
    const float* CC = ly;             // [i*64+j] = dot(Cz_i, Cz_j)

    float A   = lx[8192 + lane];      // dot(xc, Wz_lane)   (init: XW)
    float D   = lx[8256 + lane];      // dot(xc, P_lane)    (init: XP)
    float AY  = ly[8192 + lane];      // dot(yc, Cz_lane)   (init: YC)
    float w2r = lx[8320 + lane];
    float u0r = lsc[lane], tssr = lsc[NL + lane], bzr = lsc[2 * NL + lane];
    float s  = lx[8384];              // |xc|^2
    float sy = ly[8384];              // |yc|^2

    float rPW = PW[lane], rPP = PP[lane], rCC = CC[lane];
    float o_u = 0.f, o_tss = 0.f, o_bz = 0.f, o_u1 = 0.f, o_t2 = 0.f, o_g = 0.f;

    for (int i = 0; i < NL; ++i) {
        int inext = (i + 1) & 63;
        float nPW = PW[inext * 64 + lane];
        float nPP = PP[inext * 64 + lane];
        float nCC = CC[inext * 64 + lane];

        float a    = rdlane(A, i);      // dot(xc_i, Wz[i])
        float d    = rdlane(D, i);      // dot(xc_i, P[i])
        float ay   = rdlane(AY, i);     // dot(yc_i, Cz[i])
        float ppii = rdlane(rPP, i);    // |P[i]|^2
        float c2   = rdlane(rCC, i);    // |Cz[i]|^2
        float w2   = rdlane(w2r, i);
        float u0   = rdlane(u0r, i);
        float tss0 = rdlane(tssr, i);
        float bzi  = rdlane(bzr, i);

        // --- inner pass 1 (input u0)
        float den1 = sqrtf(fmaxf(w2 + 2.f * u0 * a + u0 * u0 * s, 0.f)) + 1e-7f;
        float tz1  = (a + u0 * s) * FRCP(den1);
        float tss1 = tss0 + tz1 * tz1;
        float t1   = tz1 * FRSQ(tss1);
        float cn1  = sqrtf(fmaxf(c2 + 2.f * t1 * ay + t1 * t1 * sy, 0.f));
        float u1   = (ay + t1 * sy) * FRCP(cn1);
        // --- inner pass 2 (input u1)
        float den2  = sqrtf(fmaxf(w2 + 2.f * u1 * a + u1 * u1 * s, 0.f)) + 1e-7f;
        float tz2   = (a + u1 * s) * FRCP(den2);
        float tss2  = tss0 + tz2 * tz2;
        float rs2   = FRSQ(tss2);
        float t2    = tz2 * rs2;
        float cn2sq = fmaxf(c2 + 2.f * t2 * ay + t2 * t2 * sy, 0.f);
        float cn2   = sqrtf(cn2sq);
        float rcn2  = FRCP(cn2);
        float u2    = (ay + t2 * sy) * rcn2;
        float bzo   = bzi + u2 * tz2;
        float b     = bzo * rs2;
        float g     = b * t2 * rcn2;

        if (lane == i) {
            o_u = u2; o_tss = tss2; o_bz = bzo;
            o_u1 = u1; o_t2 = t2; o_g = g;
        }

        // --- deflate: xc' = f*xc - t2*P[i],  yc' = fy*yc - g*Cz[i]
        float f  = 1.f - t2 * t2;
        float fy = 1.f - g * t2;
        s  = f * f * s - 2.f * f * t2 * d + t2 * t2 * ppii;
        sy = sy - 2.f * g * (ay + t2 * sy) + g * g * cn2sq;
        A  = fmaf(-t2, rPW, f * A);
        D  = fmaf(-t2, rPP, f * D);
        AY = fmaf(-g,  rCC, fy * AY);

        rPW = nPW; rPP = nPP; rCC = nCC;
    }

    out_u[lane]   = o_u;
    out_tss[lane] = o_tss;
    out_bz[lane]  = o_bz;
    coef[lane]          = o_u1;
    coef[NL + lane]     = o_t2;
    coef[2 * NL + lane] = o_g;
}

// ---------------------------------------------------------------------------
// Per-column recurrence, scalar columns for max TLP (512+8 blocks x 256).
// Blocks [0,512): Wz_new/P_new + mu_x fixup.  [512,520): Cz_new + mu_y.
__global__ __launch_bounds__(256) void expand(
    const float* __restrict__ P, const float* __restrict__ Wz,
    const float* __restrict__ x, const float* __restrict__ Cz,
    const float* __restrict__ y, const float* __restrict__ coef,
    float* __restrict__ xc0_mux,     // in: xc0, out: mu_x (same slot)
    float* __restrict__ yc0_muy,     // in: yc0, out: mu_y (same slot)
    float* __restrict__ outW, float* __restrict__ outP, float* __restrict__ outC)
{
    __shared__ float cA[NL], cB[NL];
    const int t = threadIdx.x;
    const int b = (int)blockIdx.x;

    if (b < 512) {
        if (t < NL) { cA[t] = coef[t]; cB[t] = coef[NL + t]; }   // u1 | t2
        const int c = b * 256 + t;
        float xc = xc0_mux[c];
        xc0_mux[c] = x[c] - xc;
        __syncthreads();
#pragma unroll 8
        for (int i = 0; i < NL; ++i) {
            size_t off = (size_t)i * NF + c;
            float wv = Wz[off], pv = P[off];
            wv = fmaf(cA[i], xc, wv);
            pv = fmaf(cB[i], xc, pv);
            outW[off] = wv;
            outP[off] = pv;
            xc = fmaf(-cB[i], pv, xc);
        }
    } else {
        if (t < NL) { cA[t] = coef[NL + t]; cB[t] = coef[2 * NL + t]; } // t2 | g
        const int c = (b - 512) * 256 + t;
        float yc = yc0_muy[c];
        yc0_muy[c] = y[c] - yc;
        __syncthreads();
#pragma unroll 8
        for (int i = 0; i < NL; ++i) {
            size_t off = (size_t)i * NT + c;
            float cv = Cz[off];
            cv = fmaf(cA[i], yc, cv);
            outC[off] = cv;
            yc = fmaf(-cB[i], cv, yc);
        }
    }
}

// ---------------------------------------------------------------------------
extern "C" void kernel_launch(void* const* d_in, const int* in_sizes, int n_in,
                              void* d_out, int out_size, void* d_ws, size_t ws_size,
                              hipStream_t stream)
{
    (void)in_sizes; (void)n_in; (void)out_size; (void)ws_size;

    const float* x    = (const float*)d_in[0];
    const float* y    = (const float*)d_in[1];
    const float* mu_x = (const float*)d_in[2];
    const float* mu_y = (const float*)d_in[3];
    const float* u    = (const float*)d_in[4];
    const float* Wz   = (const float*)d_in[5];
    const float* Cz   = (const float*)d_in[6];
    const float* tss  = (const float*)d_in[7];
    const float* bz   = (const float*)d_in[8];
    const float* P    = (const float*)d_in[9];
    const int*   n    = (const int*)d_in[10];

    float* out = (float*)d_out;
    float* ws  = (float*)d_ws;

    float* xc0   = out + O_MUX;             // stashed in mu_x slot until expand
    float* yc0   = out + O_MUY;
    // scratch in dead output regions (consumed before expand overwrites):
    float* part0 = out + O_P;                         // 512*PSIZE
    float* mid   = part0 + (size_t)512 * PSIZE;       //  64*PSIZE
    float* partY = mid   + (size_t)NMID * PSIZE;      //  16*PSIZE (< 8.39M ok)
    float* part1 = out + O_WZ;                        // 512*PSIZE (< 8.39M ok)
    float* finX  = ws + W_FINX;
    float* finY  = ws + W_FINY;
    float* coef  = ws + W_COEF;

    gram_partial<<<NBX, 256, 0, stream>>>(P,  Wz, x, mu_x, n, NF, NF / NBX,
                                          part0, part1, xc0);
    gram_partial<<<NBY, 256, 0, stream>>>(Cz, Cz, y, mu_y, n, NT, NT / NBY,
                                          partY, partY, yc0);

    gram_reduceA<<<33 * NMID, 256, 0, stream>>>(part0, part1, mid);
    gram_reduceB<<<66, 256, 0, stream>>>(mid, partY, finX, finY);

    recursion<<<1, 256, 0, stream>>>(finX, finY, u, tss, bz,
                                     out + O_U, out + O_TSS, out + O_BZ, coef);

    expand<<<520, 256, 0, stream>>>(P, Wz, x, Cz, y, coef,
                                    xc0, yc0,
                                    out + O_WZ, out + O_P, out + O_CZ);
}

// Round 7
// 226.298 us; speedup vs baseline: 4.1108x; 4.1108x over previous
//
#include <hip/hip_runtime.h>

// ---------------------------------------------------------------------------
// IPLS partial_fit, algebraically restructured.
//
//   xc0 = r*(x - mu),  r = n/(n+1);  mu_new = x - xc0
//   scan scalars from Grams: PW=P@Wz^T, PP=P@P^T, XW=Wz@xc0, XP=P@xc0,
//     W2=diag(Wz@Wz^T), s0=|xc0|^2, CC=Cz@Cz^T, YC=Cz@yc0, sy0=|yc0|^2
//   recursion keeps running dots A_j=dot(xc,Wz_j), D_j=dot(xc,P_j),
//     AY_j=dot(yc,Cz_j) updated lane-parallel per deflation (no shuffles).
//   big outputs via per-column recurrence driven by (u1,t2,g).
//
// Pipeline (5 launches):
//   gram_partial : fused Y[0,16) + X[16,528); BK=64 (35KB LDS -> >=3 blk/CU,
//                  single scheduling round).  NO launch_bounds min-occupancy:
//                  the 128-float accumulator set MUST NOT spill (round-6
//                  lesson: forcing 4 blk/CU -> 2.7GB scratch traffic, 617us).
//   gram_reduceA : 33x32 blocks, 512 X-partials -> 32 mids
//   gram_reduceB : 32 mids -> finX, 16 Y-partials -> finY
//   recursion    : 1 wave serial scan, readlane broadcasts only
//   expand       : scalar-column recurrence, 520 blocks x 256
// ---------------------------------------------------------------------------

#define NF 131072
#define NT 2048
#define NL 64

#define PSIZE 8385      // 4096 PW + 4096 PP + 64 XW + 64 XP + 64 W2 + 1 s0
#define NBX 512
#define NBY 16
#define NMID 32
#define REDK 16
#define BK 64
#define LDST 68         // k-row stride (floats): 16B-aligned b128 reads

// d_out offsets (floats), reference return order
#define O_MUX 0
#define O_MUY 131072
#define O_U   133120
#define O_WZ  133184
#define O_CZ  8521792
#define O_TSS 8652864
#define O_BZ  8652928
#define O_P   8652992

// d_ws offsets (floats)
#define W_FINX 0
#define W_FINY 8385
#define W_COEF 16770    // u1[64] | t2[64] | g[64]

__device__ __forceinline__ float rdlane(float v, int l) {
    return __int_as_float(__builtin_amdgcn_readlane(__float_as_int(v), l));
}
#define FRCP(x) __builtin_amdgcn_rcpf(x)
#define FRSQ(x) __builtin_amdgcn_rsqf(x)

// ---------------------------------------------------------------------------
// Partial Grams, centering fused.  Blocks [0,NBY): A=B=Cz (K=NT, KC=128);
// blocks [NBY,NBY+NBX): A=P, B=Wz (K=NF, KC=256).  256 threads = 4 waves,
// each wave a k-quarter of each BK=64 tile; 8x8 per-lane output tile for
// BOTH PW and PP (128 accumulator floats -> needs the full unified RF).
__global__ __launch_bounds__(256) void gram_partial(
    const float* __restrict__ PX, const float* __restrict__ WzX,
    const float* __restrict__ xsX, const float* __restrict__ musX,
    const float* __restrict__ CzY, const float* __restrict__ ysY,
    const float* __restrict__ musY, const int* __restrict__ np,
    float* __restrict__ partX, float* __restrict__ voutX,
    float* __restrict__ partY, float* __restrict__ voutY)
{
    __shared__ float lds[2 * BK * LDST + BK];   // 8768 floats = 35 KB
    float* ldsA = lds;
    float* ldsB = lds + BK * LDST;
    float* ldsV = lds + 2 * BK * LDST;

    const bool isY = (int)blockIdx.x < NBY;
    const float* A   = isY ? CzY  : PX;
    const float* B   = isY ? CzY  : WzX;
    const float* xs  = isY ? ysY  : xsX;
    const float* mus = isY ? musY : musX;
    float* vout      = isY ? voutY : voutX;
    const int K   = isY ? NT : NF;
    const int KC  = isY ? 128 : 256;
    const int bid = isY ? (int)blockIdx.x : (int)blockIdx.x - NBY;
    float* po = (isY ? partY : partX) + (size_t)bid * PSIZE;

    const int t    = threadIdx.x;
    const int w    = t >> 6;
    const int lane = t & 63;
    const int j0   = lane & 56;          // A-row base  {0,8,...,56}
    const int i0   = (lane & 7) << 3;    // B-row base  {0,8,...,56}

    const float nf = (float)(*np);
    const float r  = nf / (nf + 1.f);

    float accPW[8][8], accPP[8][8];
    float accXW[8], accXP[8], accW2[8], accS0 = 0.f;
#pragma unroll
    for (int s = 0; s < 8; ++s) {
        accXW[s] = 0.f; accXP[s] = 0.f; accW2[s] = 0.f;
#pragma unroll
        for (int q = 0; q < 8; ++q) { accPW[s][q] = 0.f; accPP[s][q] = 0.f; }
    }

    const int kbase  = bid * KC;
    const int ntiles = KC / BK;                  // 4 (X) or 2 (Y)
    // staging map: bijective (row, c4) over 16 rows x 16 float4-cols; the
    // m-loop adds row bits 4-5.  Consecutive lanes hit different rows ->
    // write conflicts stay 2-way (free).
    const int rbase = (t & 7) | ((t >> 4) & 8);
    const int c4    = ((t >> 3) & 15) << 2;

    for (int tile = 0; tile < ntiles; ++tile) {
        const int k0 = kbase + tile * BK;
        if (tile) __syncthreads();
#pragma unroll
        for (int m = 0; m < 4; ++m) {
            int row = rbase | (m << 4);
            const float4 av = *(const float4*)(A + (size_t)row * K + (k0 + c4));
            const float4 bv = *(const float4*)(B + (size_t)row * K + (k0 + c4));
            ldsA[(c4 + 0) * LDST + row] = av.x;
            ldsA[(c4 + 1) * LDST + row] = av.y;
            ldsA[(c4 + 2) * LDST + row] = av.z;
            ldsA[(c4 + 3) * LDST + row] = av.w;
            ldsB[(c4 + 0) * LDST + row] = bv.x;
            ldsB[(c4 + 1) * LDST + row] = bv.y;
            ldsB[(c4 + 2) * LDST + row] = bv.z;
            ldsB[(c4 + 3) * LDST + row] = bv.w;
        }
        if (t < BK) {
            float val = r * (xs[k0 + t] - mus[k0 + t]);   // centered sample
            ldsV[t] = val;
            vout[k0 + t] = val;                            // stash for expand
        }
        __syncthreads();

        const int kend = w * 16 + 16;
        for (int kk = w * 16; kk < kend; ++kk) {
            const float* bA = ldsA + kk * LDST;
            const float* bB = ldsB + kk * LDST;
            float4 a0 = *(const float4*)(bA + j0);
            float4 a1 = *(const float4*)(bA + j0 + 4);
            float4 b0 = *(const float4*)(bB + i0);
            float4 b1 = *(const float4*)(bB + i0 + 4);
            float4 c0 = *(const float4*)(bA + i0);
            float4 c1 = *(const float4*)(bA + i0 + 4);
            float aj[8] = {a0.x,a0.y,a0.z,a0.w,a1.x,a1.y,a1.z,a1.w};
            float bi[8] = {b0.x,b0.y,b0.z,b0.w,b1.x,b1.y,b1.z,b1.w};
            float ci[8] = {c0.x,c0.y,c0.z,c0.w,c1.x,c1.y,c1.z,c1.w};
#pragma unroll
            for (int s = 0; s < 8; ++s)
#pragma unroll
                for (int q = 0; q < 8; ++q) {
                    accPW[s][q] = fmaf(aj[s], bi[q], accPW[s][q]);
                    accPP[s][q] = fmaf(aj[s], ci[q], accPP[s][q]);
                }
            float vv = ldsV[kk];
            if (j0 == 0) {
#pragma unroll
                for (int q = 0; q < 8; ++q) accXW[q] = fmaf(vv, bi[q], accXW[q]);
            }
            if (j0 == 8) {
#pragma unroll
                for (int q = 0; q < 8; ++q) accW2[q] = fmaf(bi[q], bi[q], accW2[q]);
            }
            if (i0 == 0) {
#pragma unroll
                for (int s = 0; s < 8; ++s) accXP[s] = fmaf(vv, aj[s], accXP[s]);
            }
            if (lane == 16) accS0 = fmaf(vv, vv, accS0);
        }
    }
    __syncthreads();

    // cross-wave reduction in 2048-float chunks (fits the 8768-float LDS)
    float* red = lds;

    // PW rows 0-31
    if (j0 < 32) {
#pragma unroll
        for (int s = 0; s < 8; ++s)
#pragma unroll
            for (int q = 0; q < 8; ++q)
                red[w * 2048 + (j0 + s) * 64 + (i0 + q)] = accPW[s][q];
    }
    __syncthreads();
    for (int o = t; o < 2048; o += 256)
        po[o] = red[o] + red[2048 + o] + red[4096 + o] + red[6144 + o];
    __syncthreads();
    // PW rows 32-63
    if (j0 >= 32) {
#pragma unroll
        for (int s = 0; s < 8; ++s)
#pragma unroll
            for (int q = 0; q < 8; ++q)
                red[w * 2048 + (j0 - 32 + s) * 64 + (i0 + q)] = accPW[s][q];
    }
    __syncthreads();
    for (int o = t; o < 2048; o += 256)
        po[2048 + o] = red[o] + red[2048 + o] + red[4096 + o] + red[6144 + o];
    __syncthreads();
    // PP rows 0-31
    if (j0 < 32) {
#pragma unroll
        for (int s = 0; s < 8; ++s)
#pragma unroll
            for (int q = 0; q < 8; ++q)
                red[w * 2048 + (j0 + s) * 64 + (i0 + q)] = accPP[s][q];
    }
    __syncthreads();
    for (int o = t; o < 2048; o += 256)
        po[4096 + o] = red[o] + red[2048 + o] + red[4096 + o] + red[6144 + o];
    __syncthreads();
    // PP rows 32-63
    if (j0 >= 32) {
#pragma unroll
        for (int s = 0; s < 8; ++s)
#pragma unroll
            for (int q = 0; q < 8; ++q)
                red[w * 2048 + (j0 - 32 + s) * 64 + (i0 + q)] = accPP[s][q];
    }
    __syncthreads();
    for (int o = t; o < 2048; o += 256)
        po[6144 + o] = red[o] + red[2048 + o] + red[4096 + o] + red[6144 + o];
    __syncthreads();
    // extras: XW[64] | XP[64] | W2[64] | s0
    if (j0 == 0) {
#pragma unroll
        for (int q = 0; q < 8; ++q) red[w * 193 + (i0 + q)] = accXW[q];
    }
    if (i0 == 0) {
#pragma unroll
        for (int s = 0; s < 8; ++s) red[w * 193 + 64 + (j0 + s)] = accXP[s];
    }
    if (j0 == 8) {
#pragma unroll
        for (int q = 0; q < 8; ++q) red[w * 193 + 128 + (i0 + q)] = accW2[q];
    }
    if (lane == 16) red[w * 193 + 192] = accS0;
    __syncthreads();
    for (int o = t; o < 193; o += 256)
        po[8192 + o] = red[o] + red[193 + o] + red[386 + o] + red[579 + o];
}

// ---------------------------------------------------------------------------
// Stage A: 512 X-partials -> 32 mids (16 each, fully unrolled).
__global__ __launch_bounds__(256) void gram_reduceA(
    const float* __restrict__ partX, float* __restrict__ mid)
{
    int ob = (int)blockIdx.x % 33;
    int kb = (int)blockIdx.x / 33;     // 0..31
    int o  = ob * 256 + threadIdx.x;
    if (o >= PSIZE) return;
    const float* p = partX + (size_t)(kb * REDK) * PSIZE + o;
    float s = 0.f;
#pragma unroll
    for (int k = 0; k < REDK; ++k) s += p[(size_t)k * PSIZE];
    mid[(size_t)kb * PSIZE + o] = s;
}

// Stage B: X 32 mids -> finX; Y 16 partials -> finY (row-major, no transpose).
__global__ __launch_bounds__(256) void gram_reduceB(
    const float* __restrict__ mid, const float* __restrict__ partY,
    float* __restrict__ finX, float* __restrict__ finY)
{
    int b = blockIdx.x;
    if (b < 33) {
        int o = b * 256 + threadIdx.x;
        if (o >= PSIZE) return;
        float s = 0.f;
#pragma unroll
        for (int k = 0; k < NMID; ++k) s += mid[(size_t)k * PSIZE + o];
        finX[o] = s;
    } else {
        int o = (b - 33) * 256 + threadIdx.x;
        if (o >= PSIZE) return;
        float s = 0.f;
#pragma unroll
        for (int k = 0; k < NBY; ++k) s += partY[(size_t)k * PSIZE + o];
        finY[o] = s;
    }
}

// ---------------------------------------------------------------------------
// 64-step serial recursion, shuffle-free. Lane j carries running dots
//   A=dot(xc,Wz_j), D=dot(xc,P_j), AY=dot(yc,Cz_j)
// updated per deflation from Gram rows; per-step scalars come from cheap
// uniform v_readlane broadcasts. 256 threads stage inputs into LDS first.
__global__ __launch_bounds__(256) void recursion(
    const float* __restrict__ finX, const float* __restrict__ finY,
    const float* __restrict__ u_in, const float* __restrict__ tss_in,
    const float* __restrict__ bz_in,
    float* __restrict__ out_u, float* __restrict__ out_tss, float* __restrict__ out_bz,
    float* __restrict__ coef)
{
    __shared__ float lx[PSIZE];       // PW | PP | XW | XP | W2 | s0
    __shared__ float ly[PSIZE];       // CC | -- | YC | -- | -- | sy0
    __shared__ float lsc[3 * NL];     // u | tss | bz

    const int t = threadIdx.x;
    for (int o = t; o < PSIZE; o += 256) { lx[o] = finX[o]; ly[o] = finY[o]; }
    if (t < NL) {
        lsc[t]          = u_in[t];
        lsc[NL + t]     = tss_in[t];
        lsc[2 * NL + t] = bz_in[t];
    }
    __syncthreads();
    if (t >= 64) return;
    const int lane = t;

    const float* PW = lx;             // [i*64+j] = dot(P_i, Wz_j)
    const float* PP = lx + 4096;      // [i*64+j] = dot(P_i, P_j)
    const float* CC = ly;             // [i*64+j] = dot(Cz_i, Cz_j)

    float A   = lx[8192 + lane];      // dot(xc, Wz_lane)   (init: XW)
    float D   = lx[8256 + lane];      // dot(xc, P_lane)    (init: XP)
    float AY  = ly[8192 + lane];      // dot(yc, Cz_lane)   (init: YC)
    float w2r = lx[8320 + lane];
    float u0r = lsc[lane], tssr = lsc[NL + lane], bzr = lsc[2 * NL + lane];
    float s  = lx[8384];              // |xc|^2
    float sy = ly[8384];              // |yc|^2

    float rPW = PW[lane], rPP = PP[lane], rCC = CC[lane];
    float o_u = 0.f, o_tss = 0.f, o_bz = 0.f, o_u1 = 0.f, o_t2 = 0.f, o_g = 0.f;

    for (int i = 0; i < NL; ++i) {
        int inext = (i + 1) & 63;
        float nPW = PW[inext * 64 + lane];
        float nPP = PP[inext * 64 + lane];
        float nCC = CC[inext * 64 + lane];

        float a    = rdlane(A, i);      // dot(xc_i, Wz[i])
        float d    = rdlane(D, i);      // dot(xc_i, P[i])
        float ay   = rdlane(AY, i);     // dot(yc_i, Cz[i])
        float ppii = rdlane(rPP, i);    // |P[i]|^2
        float c2   = rdlane(rCC, i);    // |Cz[i]|^2
        float w2   = rdlane(w2r, i);
        float u0   = rdlane(u0r, i);
        float tss0 = rdlane(tssr, i);
        float bzi  = rdlane(bzr, i);

        // --- inner pass 1 (input u0)
        float den1 = sqrtf(fmaxf(w2 + 2.f * u0 * a + u0 * u0 * s, 0.f)) + 1e-7f;
        float tz1  = (a + u0 * s) * FRCP(den1);
        float tss1 = tss0 + tz1 * tz1;
        float t1   = tz1 * FRSQ(tss1);
        float cn1  = sqrtf(fmaxf(c2 + 2.f * t1 * ay + t1 * t1 * sy, 0.f));
        float u1   = (ay + t1 * sy) * FRCP(cn1);
        // --- inner pass 2 (input u1)
        float den2  = sqrtf(fmaxf(w2 + 2.f * u1 * a + u1 * u1 * s, 0.f)) + 1e-7f;
        float tz2   = (a + u1 * s) * FRCP(den2);
        float tss2  = tss0 + tz2 * tz2;
        float rs2   = FRSQ(tss2);
        float t2    = tz2 * rs2;
        float cn2sq = fmaxf(c2 + 2.f * t2 * ay + t2 * t2 * sy, 0.f);
        float cn2   = sqrtf(cn2sq);
        float rcn2  = FRCP(cn2);
        float u2    = (ay + t2 * sy) * rcn2;
        float bzo   = bzi + u2 * tz2;
        float b     = bzo * rs2;
        float g     = b * t2 * rcn2;

        if (lane == i) {
            o_u = u2; o_tss = tss2; o_bz = bzo;
            o_u1 = u1; o_t2 = t2; o_g = g;
        }

        // --- deflate: xc' = f*xc - t2*P[i],  yc' = fy*yc - g*Cz[i]
        float f  = 1.f - t2 * t2;
        float fy = 1.f - g * t2;
        s  = f * f * s - 2.f * f * t2 * d + t2 * t2 * ppii;
        sy = sy - 2.f * g * (ay + t2 * sy) + g * g * cn2sq;
        A  = fmaf(-t2, rPW, f * A);
        D  = fmaf(-t2, rPP, f * D);
        AY = fmaf(-g,  rCC, fy * AY);

        rPW = nPW; rPP = nPP; rCC = nCC;
    }

    out_u[lane]   = o_u;
    out_tss[lane] = o_tss;
    out_bz[lane]  = o_bz;
    coef[lane]          = o_u1;
    coef[NL + lane]     = o_t2;
    coef[2 * NL + lane] = o_g;
}

// ---------------------------------------------------------------------------
// Per-column recurrence, scalar columns for max TLP (512+8 blocks x 256).
// Blocks [0,512): Wz_new/P_new + mu_x fixup.  [512,520): Cz_new + mu_y.
__global__ __launch_bounds__(256) void expand(
    const float* __restrict__ P, const float* __restrict__ Wz,
    const float* __restrict__ x, const float* __restrict__ Cz,
    const float* __restrict__ y, const float* __restrict__ coef,
    float* __restrict__ xc0_mux,     // in: xc0, out: mu_x (same slot)
    float* __restrict__ yc0_muy,     // in: yc0, out: mu_y (same slot)
    float* __restrict__ outW, float* __restrict__ outP, float* __restrict__ outC)
{
    __shared__ float cA[NL], cB[NL];
    const int t = threadIdx.x;
    const int b = (int)blockIdx.x;

    if (b < 512) {
        if (t < NL) { cA[t] = coef[t]; cB[t] = coef[NL + t]; }   // u1 | t2
        const int c = b * 256 + t;
        float xc = xc0_mux[c];
        xc0_mux[c] = x[c] - xc;
        __syncthreads();
#pragma unroll 8
        for (int i = 0; i < NL; ++i) {
            size_t off = (size_t)i * NF + c;
            float wv = Wz[off], pv = P[off];
            wv = fmaf(cA[i], xc, wv);
            pv = fmaf(cB[i], xc, pv);
            outW[off] = wv;
            outP[off] = pv;
            xc = fmaf(-cB[i], pv, xc);
        }
    } else {
        if (t < NL) { cA[t] = coef[NL + t]; cB[t] = coef[2 * NL + t]; } // t2 | g
        const int c = (b - 512) * 256 + t;
        float yc = yc0_muy[c];
        yc0_muy[c] = y[c] - yc;
        __syncthreads();
#pragma unroll 8
        for (int i = 0; i < NL; ++i) {
            size_t off = (size_t)i * NT + c;
            float cv = Cz[off];
            cv = fmaf(cA[i], yc, cv);
            outC[off] = cv;
            yc = fmaf(-cB[i], cv, yc);
        }
    }
}

// ---------------------------------------------------------------------------
extern "C" void kernel_launch(void* const* d_in, const int* in_sizes, int n_in,
                              void* d_out, int out_size, void* d_ws, size_t ws_size,
                              hipStream_t stream)
{
    (void)in_sizes; (void)n_in; (void)out_size; (void)ws_size;

    const float* x    = (const float*)d_in[0];
    const float* y    = (const float*)d_in[1];
    const float* mu_x = (const float*)d_in[2];
    const float* mu_y = (const float*)d_in[3];
    const float* u    = (const float*)d_in[4];
    const float* Wz   = (const float*)d_in[5];
    const float* Cz   = (const float*)d_in[6];
    const float* tss  = (const float*)d_in[7];
    const float* bz   = (const float*)d_in[8];
    const float* P    = (const float*)d_in[9];
    const int*   n    = (const int*)d_in[10];

    float* out = (float*)d_out;
    float* ws  = (float*)d_ws;

    float* xc0   = out + O_MUX;             // stashed in mu_x slot until expand
    float* yc0   = out + O_MUY;
    // scratch in the dead P_new output region (consumed before expand writes):
    float* part0 = out + O_P;                         // 512*PSIZE = 4.29M
    float* mid   = part0 + (size_t)NBX * PSIZE;       //  32*PSIZE = 268K
    float* partY = mid   + (size_t)NMID * PSIZE;      //  16*PSIZE = 134K  (<8.39M ok)
    float* finX  = ws + W_FINX;
    float* finY  = ws + W_FINY;
    float* coef  = ws + W_COEF;

    gram_partial<<<NBY + NBX, 256, 0, stream>>>(P, Wz, x, mu_x,
                                                Cz, y, mu_y, n,
                                                part0, xc0, partY, yc0);

    gram_reduceA<<<33 * NMID, 256, 0, stream>>>(part0, mid);
    gram_reduceB<<<66, 256, 0, stream>>>(mid, partY, finX, finY);

    recursion<<<1, 256, 0, stream>>>(finX, finY, u, tss, bz,
                                     out + O_U, out + O_TSS, out + O_BZ, coef);

    expand<<<520, 256, 0, stream>>>(P, Wz, x, Cz, y, coef,
                                    xc0, yc0,
                                    out + O_WZ, out + O_P, out + O_CZ);
}